// Round 4
// baseline (288.026 us; speedup 1.0000x reference)
//
#include <hip/hip_runtime.h>
#include <hip/hip_bf16.h>

#define N_PTS 12288
#define DIM   64
#define KSEL  16
#define EPS_F 1e-5f
#define TMARGIN 2.0f   // covers 2x bf16 cross-pair screen noise (proven r1-r3)

typedef __bf16 bf16x8 __attribute__((ext_vector_type(8)));
typedef float  f32x4  __attribute__((ext_vector_type(4)));

// ---------------------------------------------------------------------------
// Kernel A: fp32 row norms sq[i], S1 = sum(sq), Sx[d] = column sums (for the
// closed-form sigma2), and a bf16 copy of coords for the MFMA screen.
// ---------------------------------------------------------------------------
__global__ __launch_bounds__(256) void stats_kernel(
    const float* __restrict__ coords,
    float* __restrict__ sq,
    float* __restrict__ s1,
    float* __restrict__ sx,
    __hip_bfloat16* __restrict__ chi)
{
    __shared__ float colsh[4][64];
    const int lane = threadIdx.x & 63;
    const int wave = threadIdx.x >> 6;
    const int gw   = blockIdx.x * 4 + wave;     // 0..2047
    float colsum = 0.f, sqsum = 0.f;
    for (int r = gw; r < N_PTS; r += 2048) {
        const float x = coords[r * DIM + lane];
        chi[r * DIM + lane] = __float2bfloat16(x);
        colsum += x;
        float p = x * x;
        #pragma unroll
        for (int off = 32; off > 0; off >>= 1)
            p += __shfl_xor(p, off, 64);
        if (lane == 0) { sq[r] = p; sqsum += p; }
    }
    colsh[wave][lane] = colsum;
    __syncthreads();
    if (wave == 0) {
        const float c = colsh[0][lane] + colsh[1][lane]
                      + colsh[2][lane] + colsh[3][lane];
        atomicAdd(&sx[lane], c);
    }
    if (lane == 0) atomicAdd(s1, sqsum);
}

// ---------------------------------------------------------------------------
// Mega kernel: one block = 32 i-rows x ALL 12288 j's. Three stages:
//  P1 (threshold): stride-2 j-tiles, branchless per-lane top-2 of screen-d2.
//     T[row] = 17th smallest of the 32 pooled segment minima + TMARGIN.
//     Certified: k-th of segment-top-2s >= k-th of sampled set >= d16(row);
//     using the 17th absorbs the single self-contaminated pool slot.
//  P2 (screen): round-3's proven private-column screen over all j-tiles.
//     Caps structurally bounded: S <= 16*CAPP + OCAP = DCAP, no drops at
//     ~50 survivors/row (lambda_seg ~3, CAPP=8 is >5 sigma).
//  P3 (merge, inline): top-32 rank-select + fp64 refine + rank-16 laplacian.
// No thresh kernel, no merge kernel, no wsknn round-trip.
// ---------------------------------------------------------------------------
__global__ __launch_bounds__(256) void mega_kernel(
    const float* __restrict__ sq,
    const __hip_bfloat16* __restrict__ chi,
    const float* __restrict__ coords,
    const float* __restrict__ pot,
    const float* __restrict__ s1,
    const float* __restrict__ sx,
    float* __restrict__ out)
{
    constexpr int CAPP  = 8;                 // private slots/lane/list
    constexpr int OCAP  = 16;                // shared overflow slots/row
    constexpr int DCAP  = 16 * CAPP + OCAP;  // 144 (structural max per row)
    constexpr int DPAD  = DCAP + 1;          // 145
    constexpr int STEPS = N_PTS / 4 / 16;    // 192 16-j tiles per wave

    __shared__ float    pool[32][32];        // [row][seg*2+{0,1}]
    __shared__ float    Trow[32];
    __shared__ unsigned buf[2 * CAPP * 256]; // [list*CAPP+p][tid]
    __shared__ int      cntT[2][4][4][16];   // [list][wave][quad][col]
    __shared__ unsigned dense[32 * DPAD];
    __shared__ unsigned ovf[32][OCAP];
    __shared__ int      ovcnt[32];
    __shared__ int      stot[32];
    __shared__ int      finj[8][32];
    __shared__ double   refd[8][32];
    __shared__ double   s_inv_den;

    const int tid  = threadIdx.x;
    const int lane = tid & 63;
    const int wave = tid >> 6;
    const int col  = lane & 15;
    const int quad = lane >> 4;
    const int ibase = (int)blockIdx.x * 32;
    const int i0 = ibase + col;
    const int i1 = ibase + 16 + col;

    if (tid == 0) {
        // sigma2 = mean(dist2 incl. +eps everywhere and +1e6 on the diagonal)
        double S1 = (double)s1[0], m2 = 0.0;
        for (int d = 0; d < DIM; ++d) { double t = (double)sx[d]; m2 += t * t; }
        const double NN = (double)N_PTS;
        s_inv_den = 1.0 / ((2.0 * NN * S1 - 2.0 * m2) / (NN * NN)
                           + 1e-5 + 1e6 / NN + 1e-5);
    }
    if (tid < 32) ovcnt[tid] = 0;

    const bf16x8* cp = (const bf16x8*)chi;
    const bf16x8 b00 = cp[i0 * 8 + quad], b01 = cp[i0 * 8 + quad + 4];
    const bf16x8 b10 = cp[i1 * 8 + quad], b11 = cp[i1 * 8 + quad + 4];
    const float base0 = sq[i0] + EPS_F;
    const float base1 = sq[i1] + EPS_F;

    const int jw = wave * (N_PTS / 4);

    // ---------------- Phase 1: stride-2 sampled top-2 per lane ----------------
    float m00 = 1e30f, m01 = 1e30f, m10 = 1e30f, m11 = 1e30f;
    {
        bf16x8 a0 = cp[(jw + col) * 8 + quad];
        bf16x8 a1 = cp[(jw + col) * 8 + quad + 4];
        float4 sqj = *(const float4*)(sq + jw + quad * 4);
        #pragma unroll 1
        for (int s = 0; s < STEPS; s += 2) {
            const int sn = (s + 2 < STEPS) ? s + 2 : s;        // clamped prefetch
            const int an = (jw + sn * 16 + col) * 8 + quad;
            const bf16x8 n0 = cp[an];
            const bf16x8 n1 = cp[an + 4];
            const float4 sqn = *(const float4*)(sq + jw + sn * 16 + quad * 4);

            f32x4 acc0 = {0.f, 0.f, 0.f, 0.f};
            acc0 = __builtin_amdgcn_mfma_f32_16x16x32_bf16(a0, b00, acc0, 0, 0, 0);
            acc0 = __builtin_amdgcn_mfma_f32_16x16x32_bf16(a1, b01, acc0, 0, 0, 0);
            f32x4 acc1 = {0.f, 0.f, 0.f, 0.f};
            acc1 = __builtin_amdgcn_mfma_f32_16x16x32_bf16(a0, b10, acc1, 0, 0, 0);
            acc1 = __builtin_amdgcn_mfma_f32_16x16x32_bf16(a1, b11, acc1, 0, 0, 0);

            #pragma unroll
            for (int r = 0; r < 4; ++r) {
                const float sj = (r == 0) ? sqj.x : (r == 1) ? sqj.y
                               : (r == 2) ? sqj.z : sqj.w;
                const float da = fmaf(-2.f, acc0[r], base0 + sj);
                const float db = fmaf(-2.f, acc1[r], base1 + sj);
                m01 = (da < m00) ? m00 : fminf(m01, da);   // branchless top-2
                m00 = fminf(m00, da);
                m11 = (db < m10) ? m10 : fminf(m11, db);
                m10 = fminf(m10, db);
            }
            a0 = n0; a1 = n1; sqj = sqn;
        }
    }
    const int seg = wave * 4 + quad;
    pool[col][seg * 2]          = m00;
    pool[col][seg * 2 + 1]      = m01;
    pool[16 + col][seg * 2]     = m10;
    pool[16 + col][seg * 2 + 1] = m11;
    __syncthreads();

    const int hw8 = tid >> 5;      // half-wave id
    const int l32 = tid & 31;
    #pragma unroll 1
    for (int pass = 0; pass < 4; ++pass) {
        const int row = pass * 8 + hw8;
        const float val = pool[row][l32];
        int rank = 0;
        #pragma unroll 8
        for (int m = 0; m < 32; ++m) {
            const float o = pool[row][m];
            rank += (o < val || (o == val && m < l32)) ? 1 : 0;
        }
        if (rank == 16) Trow[row] = val + TMARGIN;   // 17th smallest, certified
    }
    __syncthreads();

    const float th0 = 0.5f * (Trow[col] - base0);     // pass iff acc > 0.5*sj - th
    const float th1 = 0.5f * (Trow[16 + col] - base1);

    // ---------------- Phase 2: full screen (round-3 structure) ----------------
    int c0 = 0, c1 = 0;
    {
        bf16x8 a0 = cp[(jw + col) * 8 + quad];
        bf16x8 a1 = cp[(jw + col) * 8 + quad + 4];
        float4 sqj = *(const float4*)(sq + jw + quad * 4);
        #pragma unroll 1
        for (int s = 0; s < STEPS; ++s) {
            const int j0 = jw + s * 16;
            const int sn = (s + 1 < STEPS) ? s + 1 : s;
            const int an = (jw + sn * 16 + col) * 8 + quad;
            const bf16x8 n0 = cp[an];
            const bf16x8 n1 = cp[an + 4];
            const float4 sqn = *(const float4*)(sq + jw + sn * 16 + quad * 4);

            f32x4 acc0 = {0.f, 0.f, 0.f, 0.f};
            acc0 = __builtin_amdgcn_mfma_f32_16x16x32_bf16(a0, b00, acc0, 0, 0, 0);
            acc0 = __builtin_amdgcn_mfma_f32_16x16x32_bf16(a1, b01, acc0, 0, 0, 0);
            f32x4 acc1 = {0.f, 0.f, 0.f, 0.f};
            acc1 = __builtin_amdgcn_mfma_f32_16x16x32_bf16(a0, b10, acc1, 0, 0, 0);
            acc1 = __builtin_amdgcn_mfma_f32_16x16x32_bf16(a1, b11, acc1, 0, 0, 0);

            const int jq = j0 + quad * 4;
            #pragma unroll
            for (int r = 0; r < 4; ++r) {
                const float sj = (r == 0) ? sqj.x : (r == 1) ? sqj.y
                               : (r == 2) ? sqj.z : sqj.w;
                const int j = jq + r;
                const float hsj = 0.5f * sj;
                // diagonal flows through (merge stage kills j==row)
                if (acc0[r] > hsj - th0) {
                    const float d2a = (base0 + sj) - 2.0f * acc0[r];
                    const unsigned pa = (__float_as_uint(d2a) & 0xFFFFC000u) | (unsigned)j;
                    if (c0 < CAPP) { buf[c0 * 256 + tid] = pa; ++c0; }
                    else { const int sl = atomicAdd(&ovcnt[col], 1);
                           if (sl < OCAP) ovf[col][sl] = pa; }
                }
                if (acc1[r] > hsj - th1) {
                    const float d2b = (base1 + sj) - 2.0f * acc1[r];
                    const unsigned pb = (__float_as_uint(d2b) & 0xFFFFC000u) | (unsigned)j;
                    if (c1 < CAPP) { buf[(CAPP + c1) * 256 + tid] = pb; ++c1; }
                    else { const int sl = atomicAdd(&ovcnt[16 + col], 1);
                           if (sl < OCAP) ovf[16 + col][sl] = pb; }
                }
            }
            a0 = n0; a1 = n1; sqj = sqn;
        }
    }
    cntT[0][wave][quad][col] = c0;
    cntT[1][wave][quad][col] = c1;
    __syncthreads();

    // compaction: prefix over the row's 16 segment counts (seg = wave*4+quad)
    {
        int base0c = 0, base1c = 0, tot0 = 0, tot1 = 0;
        #pragma unroll
        for (int s = 0; s < 16; ++s) {
            const int c0s = cntT[0][s >> 2][s & 3][col];
            const int c1s = cntT[1][s >> 2][s & 3][col];
            if (s < seg) { base0c += c0s; base1c += c1s; }
            tot0 += c0s; tot1 += c1s;
        }
        for (int p = 0; p < c0; ++p)
            dense[col * DPAD + base0c + p] = buf[p * 256 + tid];
        for (int p = 0; p < c1; ++p)
            dense[(16 + col) * DPAD + base1c + p] = buf[(CAPP + p) * 256 + tid];
        if (wave == 0 && quad == 0) {        // 16 lanes finalize both lists
            const int ov0 = ovcnt[col]      < OCAP ? ovcnt[col]      : OCAP;
            const int ov1 = ovcnt[16 + col] < OCAP ? ovcnt[16 + col] : OCAP;
            for (int o = 0; o < ov0; ++o) dense[col * DPAD + tot0 + o]        = ovf[col][o];
            for (int o = 0; o < ov1; ++o) dense[(16 + col) * DPAD + tot1 + o] = ovf[16 + col][o];
            stot[col]      = tot0 + ov0;
            stot[16 + col] = tot1 + ov1;
        }
    }
    __syncthreads();

    // ---------------- Phase 3: inline merge (8 rows per pass) ----------------
    const double inv_den = s_inv_den;
    #pragma unroll 1
    for (int pass = 0; pass < 4; ++pass) {
        const int row  = pass * 8 + hw8;
        const int grow = ibase + row;
        const int S    = stot[row];
        finj[hw8][l32] = grow;               // default: self -> inert slot

        // broadcast rank-select top-32 (values unique: j embedded)
        const unsigned* drow = dense + row * DPAD;
        unsigned cv[5]; int rk[5];
        #pragma unroll
        for (int t = 0; t < 5; ++t) {
            cv[t] = (t * 32 + l32 < S) ? drow[t * 32 + l32] : 0xFFFFFFFFu;
            rk[t] = 0;
        }
        #pragma unroll 4
        for (int m = 0; m < S; ++m) {
            const unsigned o = drow[m];
            #pragma unroll
            for (int t = 0; t < 5; ++t) rk[t] += (o < cv[t]) ? 1 : 0;
        }
        #pragma unroll
        for (int t = 0; t < 5; ++t)
            if (rk[t] < 32 && cv[t] != 0xFFFFFFFFu)
                finj[hw8][rk[t]] = (int)(cv[t] & 0x3FFFu);
        __syncthreads();

        // fp64 refine (dot + both norms in one pass) + rank-16 + laplacian
        const int j = finj[hw8][l32];
        const float4* xi = (const float4*)(coords + grow * DIM);
        const float4* xj = (const float4*)(coords + j * DIM);
        double dot = 0.0, sqi = 0.0, sqj = 0.0;
        #pragma unroll
        for (int q = 0; q < DIM / 4; ++q) {
            const float4 a = xi[q], b = xj[q];
            dot += (double)a.x * (double)b.x + (double)a.y * (double)b.y
                 + (double)a.z * (double)b.z + (double)a.w * (double)b.w;
            sqi += (double)a.x * (double)a.x + (double)a.y * (double)a.y
                 + (double)a.z * (double)a.z + (double)a.w * (double)a.w;
            sqj += (double)b.x * (double)b.x + (double)b.y * (double)b.y
                 + (double)b.z * (double)b.z + (double)b.w * (double)b.w;
        }
        double d2 = sqi + sqj + 1e-5 - 2.0 * dot;
        if (j == grow) d2 = 1e300;           // self / pad slots
        refd[hw8][l32] = d2;
        __syncthreads();

        int rank = 0;
        #pragma unroll 1
        for (int m = 0; m < 32; ++m) {
            const double o = refd[hw8][m];
            rank += (o < d2 || (o == d2 && m < l32)) ? 1 : 0;
        }
        const double w = exp(-d2 * inv_den);
        double contrib = (rank < KSEL && j != grow)
                       ? w * ((double)pot[j] - (double)pot[grow]) : 0.0;
        #pragma unroll
        for (int off = 1; off < 32; off <<= 1)
            contrib += __shfl_xor(contrib, off, 64);
        if (l32 == 0) out[grow] = (float)contrib;
        __syncthreads();                      // finj/refd reused next pass
    }
}

extern "C" void kernel_launch(void* const* d_in, const int* in_sizes, int n_in,
                              void* d_out, int out_size, void* d_ws, size_t ws_size,
                              hipStream_t stream)
{
    (void)in_sizes; (void)n_in; (void)out_size; (void)ws_size;
    const float* coords = (const float*)d_in[0];
    const float* pot    = (const float*)d_in[1];
    // d_in[2] is k (always 16, compiled in as KSEL)

    char* w = (char*)d_ws;
    float* sq = (float*)w;                             // [N_PTS]      49152 B
    float* s1 = (float*)(w + 49152);                   // [1]
    float* sx = (float*)(w + 49156);                   // [DIM]
    __hip_bfloat16* chi = (__hip_bfloat16*)(w + 49424);// [N*DIM] bf16 1.57 MB
    // total workspace need: ~1.62 MB (well under every tier)

    hipMemsetAsync((void*)s1, 0, (1 + DIM) * sizeof(float), stream);
    stats_kernel<<<dim3(512), dim3(256), 0, stream>>>(coords, sq, s1, sx, chi);
    mega_kernel<<<dim3(N_PTS / 32), dim3(256), 0, stream>>>(
        sq, chi, coords, pot, s1, sx, (float*)d_out);
}